// Round 11
// baseline (509.932 us; speedup 1.0000x reference)
//
#include <hip/hip_runtime.h>

#define HD 128
#define EPB 4096   // edges per block in hist/fill passes
#define BUK 256    // dsts per bucket

typedef __attribute__((ext_vector_type(8))) short bf16x8;
typedef __attribute__((ext_vector_type(4))) float f32x4;
typedef __attribute__((ext_vector_type(4))) unsigned int u32x4;

static __device__ __forceinline__ float bf2f(unsigned short u) {
    union { unsigned int i; float f; } c; c.i = ((unsigned int)u) << 16; return c.f;
}
static __device__ __forceinline__ unsigned short f2bf(float f) {
    union { float f; unsigned int i; } c; c.f = f;
    unsigned int lsb = (c.i >> 16) & 1;
    c.i += 0x7fffu + lsb;
    return (unsigned short)(c.i >> 16);
}

// ------- fused prep: spline | U_r = W_r @ L^T | x->bf16 | edge histogram ------
__global__ __launch_bounds__(256) void prep(
    const float* __restrict__ knots, const float* __restrict__ vals,
    float* __restrict__ M,
    const float* __restrict__ W1, const float* __restrict__ W2,
    const float* __restrict__ l1, const float* __restrict__ l2,
    const float* __restrict__ kw, unsigned short* __restrict__ Wt,
    const float* __restrict__ x, unsigned short* __restrict__ xb, long nxh,
    const int* __restrict__ e0, const int* __restrict__ e1,
    const int* __restrict__ e2, int* __restrict__ Hmat,
    int E, int NBLK, int NBUK, int histBase) {
    const int bid = blockIdx.x;
    const int t = threadIdx.x;
    if (bid == 0) {
        if (t < 128) {
            int f = t;
            float kn[5], v[5];
#pragma unroll
            for (int i = 0; i < 5; ++i) { kn[i] = knots[i]; v[i] = vals[f * 5 + i]; }
            float h[4], sl[4];
#pragma unroll
            for (int i = 0; i < 4; ++i) { h[i] = kn[i+1] - kn[i]; sl[i] = (v[i+1] - v[i]) / h[i]; }
            float r0 = 6.f * (sl[1] - sl[0]);
            float r1 = 6.f * (sl[2] - sl[1]);
            float r2 = 6.f * (sl[3] - sl[2]);
            float d0 = 2.f * (h[0] + h[1]), d1 = 2.f * (h[1] + h[2]), d2 = 2.f * (h[2] + h[3]);
            float e0v = h[1], e1v = h[2];
            float w1 = e0v / d0;  float d1p = d1 - w1 * e0v;  float r1p = r1 - w1 * r0;
            float w2 = e1v / d1p; float d2p = d2 - w2 * e1v;  float r2p = r2 - w2 * r1p;
            float x2 = r2p / d2p;
            float x1 = (r1p - e1v * x2) / d1p;
            float x0 = (r0 - e0v * x1) / d0;
            M[f*5+0] = 0.f; M[f*5+1] = x0; M[f*5+2] = x1; M[f*5+3] = x2; M[f*5+4] = 0.f;
        }
        return;
    }
    if (bid < 897) {
        __shared__ float Lrow[HD];
        const int id = bid - 1;
        const int mat = id >> 7, c = id & 127;
        if (mat == 6) {
            if (t < 128) Wt[(long)6 * 16384 + c * HD + t] = f2bf(kw[c * HD + t]);
            return;
        }
        const float* Wr = (mat < 3) ? (W1 + (long)mat * 16384) : (W2 + (long)(mat - 3) * 16384);
        const float* L  = (mat < 3) ? l1 : l2;
        if (t < 128) Lrow[t] = L[c * HD + t];
        __syncthreads();
        if (t < 128) {
            float s = 0.f;
#pragma unroll 8
            for (int j = 0; j < HD; ++j) s += Wr[t * HD + j] * Lrow[j];
            Wt[(long)mat * 16384 + c * HD + t] = f2bf(s);
        }
        return;
    }
    if (bid < histBase) {
        long i = ((long)(bid - 897) * 256 + t) * 8;
        if (i < nxh) {
            float4 f0 = *(const float4*)(x + i);
            float4 f1 = *(const float4*)(x + i + 4);
            ushort4 o0, o1;
            o0.x = f2bf(f0.x); o0.y = f2bf(f0.y); o0.z = f2bf(f0.z); o0.w = f2bf(f0.w);
            o1.x = f2bf(f1.x); o1.y = f2bf(f1.y); o1.z = f2bf(f1.z); o1.w = f2bf(f1.w);
            *(ushort4*)(xb + i) = o0;
            *(ushort4*)(xb + i + 4) = o1;
        }
        return;
    }
    // histogram part
    __shared__ int hist[256];
    const int hid = bid - histBase;
    const int r = hid / NBLK, blk = hid - r * NBLK;
    const int* dst = (r == 0) ? e0 : ((r == 1) ? e1 : e2);
    if (t < NBUK) hist[t] = 0;
    __syncthreads();
    const int s0 = blk * EPB, s1 = min(s0 + EPB, E);
    for (int e = s0 + t; e < s1; e += 256) atomicAdd(&hist[dst[e] >> 8], 1);
    __syncthreads();
    if (t < NBUK) Hmat[((long)r * NBUK + t) * NBLK + blk] = hist[t];
}

// ---------------- MFMA GEMM -----------------------------------------------------
// A layout: Ag[rel][cg][N][16] bf16 (cg = 8 column groups of 16 feats).
// MODE 1: hb(n x 128, bf16) = relu( Ag @ [U0;U1;U2] + bias )
// MODE 3: h2 = relu(Ag @ [U2] + bias) [LDS]; kanlin = h2 @ kanW + bias2;
//         affine -> spline -> dot fc_w -> out (n,)
template <int MODE>
__global__ __launch_bounds__(256) void mfma_gemm(
    const unsigned short* __restrict__ A, const unsigned short* __restrict__ Wt,
    const unsigned short* __restrict__ Wt2,
    void* __restrict__ Out, const float* __restrict__ bias,
    const float* __restrict__ bias2,
    const float* __restrict__ alpha, const float* __restrict__ beta,
    const float* __restrict__ knots, const float* __restrict__ vals,
    const float* __restrict__ Msp, const float* __restrict__ fcw,
    const float* __restrict__ fcb, int n) {
    __shared__ unsigned short As[64 * HD];   // 16 KB, XOR-swizzled
    __shared__ unsigned short Ws[HD * HD];   // 32 KB, XOR-swizzled
    const int t = threadIdx.x;
    const int row0 = blockIdx.x * 64;
    const int w = t >> 6;
    const int lane = t & 63;
    const int m = lane & 15;
    const int g = lane >> 4;
    const int sw = (m & 7) << 4;

    f32x4 acc[8];
#pragma unroll
    for (int ct = 0; ct < 8; ++ct) acc[ct] = (f32x4){0.f, 0.f, 0.f, 0.f};

#pragma unroll
    for (int rel = 0; rel < 3; ++rel) {
        if (rel) __syncthreads();
        const unsigned short* Wg = Wt + (long)rel * 16384;
        for (int i = t; i < 2048; i += 256) {
            u32x4 v = *(const u32x4*)(Wg + i * 8);
            int byte = (i * 16) ^ (((i >> 4) & 7) << 4);
            *(u32x4*)((char*)Ws + byte) = v;
        }
        // A stage: plane-contiguous reads from Ag[rel][cg][N][16]
        for (int i = t; i < 1024; i += 256) {
            int cg = i >> 7;           // 0..7
            int j  = i & 127;
            int rr = j >> 1;           // 0..63
            int half = j & 1;
            int row = row0 + rr;
            u32x4 v = (u32x4){0u, 0u, 0u, 0u};
            if (row < n)
                v = __builtin_nontemporal_load(
                    (const u32x4*)(A + (((long)(rel * 8 + cg) * n + row) << 4) + half * 8));
            int k8 = cg * 2 + half;    // 8-feat chunk 0..15
            int byte = (rr * 256 + k8 * 16) ^ ((rr & 7) << 4);
            *(u32x4*)((char*)As + byte) = v;
        }
        __syncthreads();
#pragma unroll
        for (int ks = 0; ks < 4; ++ks) {
            const int kb = ks * 64 + g * 16;
            bf16x8 af = *(const bf16x8*)((const char*)As + ((((w * 16 + m) << 8) + kb) ^ sw));
#pragma unroll
            for (int ct = 0; ct < 8; ++ct) {
                bf16x8 bf = *(const bf16x8*)((const char*)Ws + ((((ct * 16 + m) << 8) + kb) ^ sw));
                acc[ct] = __builtin_amdgcn_mfma_f32_16x16x32_bf16(af, bf, acc[ct], 0, 0, 0);
            }
        }
    }

    if (MODE == 1) {
        unsigned short* C = (unsigned short*)Out;
#pragma unroll
        for (int ct = 0; ct < 8; ++ct) {
            float bv = bias[ct * 16 + m];
#pragma unroll
            for (int r = 0; r < 4; ++r) {
                int row = row0 + w * 16 + g * 4 + r;
                if (row < n)
                    C[(long)row * HD + ct * 16 + m] = f2bf(fmaxf(acc[ct][r] + bv, 0.f));
            }
        }
    } else {
        // ---- phase 2: h2 (LDS) @ kanW, then spline + fc ----
        __syncthreads();   // all phase-1 As reads done
#pragma unroll
        for (int ct = 0; ct < 8; ++ct) {
            float bv = bias[ct * 16 + m];
#pragma unroll
            for (int r = 0; r < 4; ++r) {
                int row = w * 16 + g * 4 + r;
                float hv = fmaxf(acc[ct][r] + bv, 0.f);
                int byte = ((row << 8) + ((ct * 16 + m) << 1)) ^ ((row & 7) << 4);
                *(unsigned short*)((char*)As + byte) = f2bf(hv);
            }
        }
        for (int i = t; i < 2048; i += 256) {
            u32x4 v = *(const u32x4*)(Wt2 + i * 8);
            int byte = (i * 16) ^ (((i >> 4) & 7) << 4);
            *(u32x4*)((char*)Ws + byte) = v;
        }
        __syncthreads();
#pragma unroll
        for (int ct = 0; ct < 8; ++ct) acc[ct] = (f32x4){0.f, 0.f, 0.f, 0.f};
#pragma unroll
        for (int ks = 0; ks < 4; ++ks) {
            const int kb = ks * 64 + g * 16;
            bf16x8 af = *(const bf16x8*)((const char*)As + ((((w * 16 + m) << 8) + kb) ^ sw));
#pragma unroll
            for (int ct = 0; ct < 8; ++ct) {
                bf16x8 bf = *(const bf16x8*)((const char*)Ws + ((((ct * 16 + m) << 8) + kb) ^ sw));
                acc[ct] = __builtin_amdgcn_mfma_f32_16x16x32_bf16(af, bf, acc[ct], 0, 0, 0);
            }
        }
        float kn[5];
#pragma unroll
        for (int i = 0; i < 5; ++i) kn[i] = knots[i];
        float part[4] = {0.f, 0.f, 0.f, 0.f};
#pragma unroll
        for (int ct = 0; ct < 8; ++ct) {
            int f = ct * 16 + m;
            float kb = bias2[f], al = alpha[f], be = beta[f], fw = fcw[f];
#pragma unroll
            for (int r = 0; r < 4; ++r) {
                float xv = al * (acc[ct][r] + kb) + be;
                int j = -1;
#pragma unroll
                for (int k = 0; k < 5; ++k) j += (xv >= kn[k]) ? 1 : 0;
                j = max(0, min(3, j));
                float t0 = kn[j], t1 = kn[j + 1];
                float hj = t1 - t0;
                float y0 = vals[f * 5 + j], y1 = vals[f * 5 + j + 1];
                float M0 = Msp[f * 5 + j], M1 = Msp[f * 5 + j + 1];
                float a = t1 - xv, b = xv - t0;
                float inv6h = 1.f / (6.f * hj);
                float s = M0 * a * a * a * inv6h + M1 * b * b * b * inv6h
                        + (y0 / hj - M0 * hj / 6.f) * a + (y1 / hj - M1 * hj / 6.f) * b;
                part[r] += s * fw;
            }
        }
#pragma unroll
        for (int o = 1; o < 16; o <<= 1) {
#pragma unroll
            for (int r = 0; r < 4; ++r) part[r] += __shfl_xor(part[r], o);
        }
        if (m == 0) {
#pragma unroll
            for (int r = 0; r < 4; ++r) {
                int row = row0 + w * 16 + g * 4 + r;
                if (row < n) ((float*)Out)[row] = part[r] + fcb[0];
            }
        }
    }
}

// ---------------- flat exclusive scan (phase A + C) ----------------------------
__global__ __launch_bounds__(256) void scanA(const int* __restrict__ cnt,
                                             int* __restrict__ S,
                                             int* __restrict__ bsum, int n) {
    __shared__ int ts[256];
    const int t = threadIdx.x;
    const int base = blockIdx.x * 2048 + t * 8;
    int v[8];
    int s = 0;
#pragma unroll
    for (int i = 0; i < 8; ++i) {
        int j = base + i;
        v[i] = (j < n) ? cnt[j] : 0;
        s += v[i];
    }
    ts[t] = s;
    __syncthreads();
    for (int off = 1; off < 256; off <<= 1) {
        int x = (t >= off) ? ts[t - off] : 0;
        __syncthreads();
        ts[t] += x;
        __syncthreads();
    }
    int excl = ts[t] - s;
#pragma unroll
    for (int i = 0; i < 8; ++i) {
        int j = base + i;
        if (j < n) S[j] = excl;
        excl += v[i];
    }
    if (t == 255) bsum[blockIdx.x] = ts[255];
}

__global__ __launch_bounds__(256) void scanC(int* __restrict__ S,
                                             const int* __restrict__ bsum,
                                             int n, int total) {
    __shared__ int red[256];
    const int t = threadIdx.x;
    int acc = 0;
    for (int b = t; b < blockIdx.x; b += 256) acc += bsum[b];
    red[t] = acc;
    __syncthreads();
    for (int o = 128; o; o >>= 1) {
        if (t < o) red[t] += red[t + o];
        __syncthreads();
    }
    const int off = red[0];
    const int base = blockIdx.x * 2048 + t * 8;
#pragma unroll
    for (int i = 0; i < 8; ++i) {
        int j = base + i;
        if (j < n) S[j] += off;
    }
    if (blockIdx.x == gridDim.x - 1 && t == 0) S[n] = total;
}

// ---------------- pass 2: write packed entries to block-private slots ----------
__global__ __launch_bounds__(256) void fill_pass(
    const int* __restrict__ e0, const int* __restrict__ e1,
    const int* __restrict__ e2, const int* __restrict__ O,
    unsigned int* __restrict__ P, int E, int NBLK, int NBUK) {
    __shared__ int cur[256];
    const int r = blockIdx.y, blk = blockIdx.x, t = threadIdx.x;
    const int* eb = (r == 0) ? e0 : ((r == 1) ? e1 : e2);
    if (t < NBUK) cur[t] = O[((long)r * NBUK + t) * NBLK + blk];
    __syncthreads();
    const int s0 = blk * EPB, s1 = min(s0 + EPB, E);
    for (int e = s0 + t; e < s1; e += 256) {
        int dst = eb[e], src = eb[E + e];
        int pos = atomicAdd(&cur[dst >> 8], 1);
        P[pos] = ((unsigned)(dst & 255) << 16) | (unsigned)src;
    }
}

// ---------------- pass 3: bucket -> dst-sorted srcs + per-dst rowptr S ---------
__global__ __launch_bounds__(256) void bucket_scatter2(
    const unsigned int* __restrict__ P, const int* __restrict__ O,
    unsigned short* __restrict__ srcs, int* __restrict__ S,
    int N, int NBUK, int NBLK, int E3) {
    __shared__ int cnt[256], pos[256], cur[256];
    const int b = blockIdx.x, r = blockIdx.y, t = threadIdx.x;
    const int d0 = b * BUK;
    const long oidx = (long)r * NBUK + b;
    const int pb = O[oidx * NBLK];
    const int pe = (oidx + 1 < (long)3 * NBUK) ? O[(oidx + 1) * NBLK] : E3;
    cnt[t] = 0;
    __syncthreads();
    for (int i = pb + t; i < pe; i += 256) atomicAdd(&cnt[P[i] >> 16], 1);
    __syncthreads();
    int v = cnt[t];
    pos[t] = v;
    __syncthreads();
    for (int off = 1; off < 256; off <<= 1) {
        int x = (t >= off) ? pos[t - off] : 0;
        __syncthreads();
        pos[t] += x;
        __syncthreads();
    }
    int start = pb + pos[t] - v;   // exclusive
    cur[t] = start;
    int d = d0 + t;
    if (d < N) S[(long)r * N + d] = start;
    __syncthreads();
    for (int i = pb + t; i < pe; i += 256) {
        unsigned pk = P[i];
        int p2 = atomicAdd(&cur[pk >> 16], 1);
        srcs[p2] = (unsigned short)(pk & 0xFFFFu);
    }
    if (b == NBUK - 1 && r == 2 && t == 0) S[(long)3 * N] = E3;
}

// ------- gather agg, XCD-pinned column split: cg = blockIdx & 7 ---------------
// block: 128 dsts x (2 lanes x 8 feats = 16 feats of column group cg).
// Out layout: Ag[rel][cg][N][16] bf16.
__global__ __launch_bounds__(256) void csr_agg3(const unsigned short* __restrict__ X,
                                                const int* __restrict__ S,
                                                const unsigned short* __restrict__ srcs,
                                                unsigned short* __restrict__ Ag, int N) {
    const int cg = blockIdx.x & 7;
    const int dgrp = blockIdx.x >> 3;
    const int pair = threadIdx.x >> 1;   // 0..127
    const int half = threadIdx.x & 1;
    const int d = dgrp * 128 + pair;
    if (d >= N) return;
    const unsigned short* Xb = X + cg * 16 + half * 8;
#pragma unroll
    for (int r = 0; r < 3; ++r) {
        const int beg = S[(long)r * N + d];
        const int end = S[(long)r * N + d + 1];
        float ac[8] = {0.f, 0.f, 0.f, 0.f, 0.f, 0.f, 0.f, 0.f};
        int e = beg;
        for (; e + 7 < end; e += 8) {
            u32x4 v0 = *(const u32x4*)(Xb + (long)srcs[e    ] * HD);
            u32x4 v1 = *(const u32x4*)(Xb + (long)srcs[e + 1] * HD);
            u32x4 v2 = *(const u32x4*)(Xb + (long)srcs[e + 2] * HD);
            u32x4 v3 = *(const u32x4*)(Xb + (long)srcs[e + 3] * HD);
            u32x4 v4 = *(const u32x4*)(Xb + (long)srcs[e + 4] * HD);
            u32x4 v5 = *(const u32x4*)(Xb + (long)srcs[e + 5] * HD);
            u32x4 v6 = *(const u32x4*)(Xb + (long)srcs[e + 6] * HD);
            u32x4 v7 = *(const u32x4*)(Xb + (long)srcs[e + 7] * HD);
#pragma unroll
            for (int c = 0; c < 4; ++c) {
                ac[2*c]   += bf2f((unsigned short)(v0[c] & 0xffff)) + bf2f((unsigned short)(v1[c] & 0xffff))
                           + bf2f((unsigned short)(v2[c] & 0xffff)) + bf2f((unsigned short)(v3[c] & 0xffff))
                           + bf2f((unsigned short)(v4[c] & 0xffff)) + bf2f((unsigned short)(v5[c] & 0xffff))
                           + bf2f((unsigned short)(v6[c] & 0xffff)) + bf2f((unsigned short)(v7[c] & 0xffff));
                ac[2*c+1] += bf2f((unsigned short)(v0[c] >> 16)) + bf2f((unsigned short)(v1[c] >> 16))
                           + bf2f((unsigned short)(v2[c] >> 16)) + bf2f((unsigned short)(v3[c] >> 16))
                           + bf2f((unsigned short)(v4[c] >> 16)) + bf2f((unsigned short)(v5[c] >> 16))
                           + bf2f((unsigned short)(v6[c] >> 16)) + bf2f((unsigned short)(v7[c] >> 16));
            }
        }
        for (; e < end; ++e) {
            u32x4 v0 = *(const u32x4*)(Xb + (long)srcs[e] * HD);
#pragma unroll
            for (int c = 0; c < 4; ++c) {
                ac[2*c]   += bf2f((unsigned short)(v0[c] & 0xffff));
                ac[2*c+1] += bf2f((unsigned short)(v0[c] >> 16));
            }
        }
        u32x4 ov;
        ov[0] = (unsigned)f2bf(ac[0]) | ((unsigned)f2bf(ac[1]) << 16);
        ov[1] = (unsigned)f2bf(ac[2]) | ((unsigned)f2bf(ac[3]) << 16);
        ov[2] = (unsigned)f2bf(ac[4]) | ((unsigned)f2bf(ac[5]) << 16);
        ov[3] = (unsigned)f2bf(ac[6]) | ((unsigned)f2bf(ac[7]) << 16);
        __builtin_nontemporal_store(ov,
            (u32x4*)&Ag[(((long)(r * 8 + cg) * N + d) << 4) + half * 8]);
    }
}

extern "C" void kernel_launch(void* const* d_in, const int* in_sizes, int n_in,
                              void* d_out, int out_size, void* d_ws, size_t ws_size,
                              hipStream_t stream) {
    const float* x       = (const float*)d_in[0];
    const int*   eA[3]   = {(const int*)d_in[1], (const int*)d_in[2], (const int*)d_in[3]};
    const float* W1      = (const float*)d_in[4];
    const float* lin1_w  = (const float*)d_in[5];
    const float* lin1_b  = (const float*)d_in[6];
    const float* W2      = (const float*)d_in[7];
    const float* lin2_w  = (const float*)d_in[8];
    const float* lin2_b  = (const float*)d_in[9];
    const float* kan_w   = (const float*)d_in[10];
    const float* kan_b   = (const float*)d_in[11];
    const float* alpha   = (const float*)d_in[12];
    const float* beta    = (const float*)d_in[13];
    const float* knots   = (const float*)d_in[14];
    const float* spline_vals = (const float*)d_in[15];
    const float* fc_w    = (const float*)d_in[16];
    const float* fc_b    = (const float*)d_in[17];

    const int N = in_sizes[0] / HD;
    const int E = in_sizes[1] / 2;
    const int NBUK = (N + BUK - 1) / BUK;
    const int NBLK = (E + EPB - 1) / EPB;
    const int nH   = 3 * NBUK * NBLK;      // histogram matrix size

    // ---- workspace carve (256B-aligned blocks) ----
    char* p = (char*)d_ws;
    auto carve = [&](size_t bytes) {
        char* q = p;
        p += (bytes + 255) & ~(size_t)255;
        return q;
    };
    float* M              = (float*)carve(4096);
    unsigned short* Wt    = (unsigned short*)carve((size_t)7 * 16384 * 2);
    int* Hmat             = (int*)carve((size_t)nH * 4);
    int* O                = (int*)carve((size_t)(nH + 1) * 4);
    int* bsum             = (int*)carve(4096);
    int* S                = (int*)carve((size_t)(3 * N + 1) * 4);
    unsigned int* P       = (unsigned int*)carve((size_t)3 * E * 4);
    unsigned short* srcs  = (unsigned short*)carve((size_t)3 * E * 2);
    unsigned short* xb    = (unsigned short*)carve((size_t)N * HD * 2);
    unsigned short* hb    = (unsigned short*)carve((size_t)N * HD * 2);
    unsigned short* Ag    = (unsigned short*)carve((size_t)N * 384 * 2);

    const long nxh = (long)N * HD;
    const int xcastB = (int)((nxh + 2047) / 2048);
    const int histBase = 1 + 896 + xcastB;
    const int prepGrid = histBase + 3 * NBLK;
    const int g64      = (N + 63) / 64;
    const int aggGrid  = 8 * ((N + 127) / 128);
    const int scanGrid = (nH + 2047) / 2048;

    // fused small precomputes + edge histogram
    prep<<<prepGrid, 256, 0, stream>>>(knots, spline_vals, M, W1, W2, lin1_w, lin2_w,
                                       kan_w, Wt, x, xb, nxh,
                                       eA[0], eA[1], eA[2], Hmat, E, NBLK, NBUK, histBase);

    // ---- edge sort into dst-sorted srcs (block-private writes throughout) ----
    scanA<<<scanGrid, 256, 0, stream>>>(Hmat, O, bsum, nH);
    scanC<<<scanGrid, 256, 0, stream>>>(O, bsum, nH, 3 * E);
    fill_pass<<<dim3(NBLK, 3), 256, 0, stream>>>(eA[0], eA[1], eA[2], O, P, E, NBLK, NBUK);
    bucket_scatter2<<<dim3(NBUK, 3), 256, 0, stream>>>(P, O, srcs, S, N, NBUK, NBLK, 3 * E);

    // ---- layer 1: Ag = [A_r x]_cat ; h1 = relu(Ag @ [U1_r] + b1) ----
    csr_agg3<<<aggGrid, 256, 0, stream>>>(xb, S, srcs, Ag, N);
    mfma_gemm<1><<<g64, 256, 0, stream>>>(Ag, Wt, nullptr, hb, lin1_b, nullptr,
                                          nullptr, nullptr, nullptr, nullptr,
                                          nullptr, nullptr, nullptr, N);

    // ---- layer 2 + KAN + spline + fc (fused) ----
    csr_agg3<<<aggGrid, 256, 0, stream>>>(hb, S, srcs, Ag, N);
    mfma_gemm<3><<<g64, 256, 0, stream>>>(Ag, Wt + (size_t)3 * 16384,
                                          Wt + (size_t)6 * 16384, d_out, lin2_b, kan_b,
                                          alpha, beta, knots, spline_vals, M,
                                          fc_w, fc_b, N);
}

// Round 12
// 293.076 us; speedup vs baseline: 1.7399x; 1.7399x over previous
//
#include <hip/hip_runtime.h>

#define HD 128
#define EPB 8192   // edges per block in hist/fill passes
#define BUK 256    // dsts per bucket

typedef __attribute__((ext_vector_type(8))) short bf16x8;
typedef __attribute__((ext_vector_type(4))) float f32x4;
typedef __attribute__((ext_vector_type(4))) unsigned int u32x4;

static __device__ __forceinline__ float bf2f(unsigned short u) {
    union { unsigned int i; float f; } c; c.i = ((unsigned int)u) << 16; return c.f;
}
static __device__ __forceinline__ unsigned short f2bf(float f) {
    union { float f; unsigned int i; } c; c.f = f;
    unsigned int lsb = (c.i >> 16) & 1;
    c.i += 0x7fffu + lsb;
    return (unsigned short)(c.i >> 16);
}

// ------- fused prep: spline | U_r = W_r @ L^T | x->bf16 | edge histogram ------
__global__ __launch_bounds__(256) void prep(
    const float* __restrict__ knots, const float* __restrict__ vals,
    float* __restrict__ M,
    const float* __restrict__ W1, const float* __restrict__ W2,
    const float* __restrict__ l1, const float* __restrict__ l2,
    const float* __restrict__ kw, unsigned short* __restrict__ Wt,
    const float* __restrict__ x, unsigned short* __restrict__ xb, long nxh,
    const int* __restrict__ e0, const int* __restrict__ e1,
    const int* __restrict__ e2, int* __restrict__ Hmat,
    int E, int NBLK, int NBUK, int histBase) {
    const int bid = blockIdx.x;
    const int t = threadIdx.x;
    if (bid == 0) {
        if (t < 128) {
            int f = t;
            float kn[5], v[5];
#pragma unroll
            for (int i = 0; i < 5; ++i) { kn[i] = knots[i]; v[i] = vals[f * 5 + i]; }
            float h[4], sl[4];
#pragma unroll
            for (int i = 0; i < 4; ++i) { h[i] = kn[i+1] - kn[i]; sl[i] = (v[i+1] - v[i]) / h[i]; }
            float r0 = 6.f * (sl[1] - sl[0]);
            float r1 = 6.f * (sl[2] - sl[1]);
            float r2 = 6.f * (sl[3] - sl[2]);
            float d0 = 2.f * (h[0] + h[1]), d1 = 2.f * (h[1] + h[2]), d2 = 2.f * (h[2] + h[3]);
            float e0v = h[1], e1v = h[2];
            float w1 = e0v / d0;  float d1p = d1 - w1 * e0v;  float r1p = r1 - w1 * r0;
            float w2 = e1v / d1p; float d2p = d2 - w2 * e1v;  float r2p = r2 - w2 * r1p;
            float x2 = r2p / d2p;
            float x1 = (r1p - e1v * x2) / d1p;
            float x0 = (r0 - e0v * x1) / d0;
            M[f*5+0] = 0.f; M[f*5+1] = x0; M[f*5+2] = x1; M[f*5+3] = x2; M[f*5+4] = 0.f;
        }
        return;
    }
    if (bid < 897) {
        __shared__ float Lrow[HD];
        const int id = bid - 1;
        const int mat = id >> 7, c = id & 127;
        if (mat == 6) {
            if (t < 128) Wt[(long)6 * 16384 + c * HD + t] = f2bf(kw[c * HD + t]);
            return;
        }
        const float* Wr = (mat < 3) ? (W1 + (long)mat * 16384) : (W2 + (long)(mat - 3) * 16384);
        const float* L  = (mat < 3) ? l1 : l2;
        if (t < 128) Lrow[t] = L[c * HD + t];
        __syncthreads();
        if (t < 128) {
            float s = 0.f;
#pragma unroll 8
            for (int j = 0; j < HD; ++j) s += Wr[t * HD + j] * Lrow[j];
            Wt[(long)mat * 16384 + c * HD + t] = f2bf(s);
        }
        return;
    }
    if (bid < histBase) {
        long i = ((long)(bid - 897) * 256 + t) * 8;
        if (i < nxh) {
            float4 f0 = *(const float4*)(x + i);
            float4 f1 = *(const float4*)(x + i + 4);
            ushort4 o0, o1;
            o0.x = f2bf(f0.x); o0.y = f2bf(f0.y); o0.z = f2bf(f0.z); o0.w = f2bf(f0.w);
            o1.x = f2bf(f1.x); o1.y = f2bf(f1.y); o1.z = f2bf(f1.z); o1.w = f2bf(f1.w);
            *(ushort4*)(xb + i) = o0;
            *(ushort4*)(xb + i + 4) = o1;
        }
        return;
    }
    // histogram part
    __shared__ int hist[256];
    const int hid = bid - histBase;
    const int r = hid / NBLK, blk = hid - r * NBLK;
    const int* dst = (r == 0) ? e0 : ((r == 1) ? e1 : e2);
    if (t < NBUK) hist[t] = 0;
    __syncthreads();
    const int s0 = blk * EPB, s1 = min(s0 + EPB, E);
    for (int e = s0 + t; e < s1; e += 256) atomicAdd(&hist[dst[e] >> 8], 1);
    __syncthreads();
    if (t < NBUK) Hmat[((long)r * NBUK + t) * NBLK + blk] = hist[t];
}

// ---------------- MFMA GEMM -----------------------------------------------------
// MODE 1: hb(n x 128, bf16) = relu( Ag(n x 384, bf16) @ [U0;U1;U2] + bias )
// MODE 3: h2 = relu(Ag @ [U2] + bias) [LDS]; kanlin = h2 @ kanW + bias2;
//         affine -> spline -> dot fc_w -> out (n,)
template <int MODE>
__global__ __launch_bounds__(256) void mfma_gemm(
    const unsigned short* __restrict__ A, const unsigned short* __restrict__ Wt,
    const unsigned short* __restrict__ Wt2,
    void* __restrict__ Out, const float* __restrict__ bias,
    const float* __restrict__ bias2,
    const float* __restrict__ alpha, const float* __restrict__ beta,
    const float* __restrict__ knots, const float* __restrict__ vals,
    const float* __restrict__ Msp, const float* __restrict__ fcw,
    const float* __restrict__ fcb, int n) {
    __shared__ unsigned short As[64 * HD];   // 16 KB, XOR-swizzled
    __shared__ unsigned short Ws[HD * HD];   // 32 KB, XOR-swizzled
    const int t = threadIdx.x;
    const int row0 = blockIdx.x * 64;
    const int w = t >> 6;
    const int lane = t & 63;
    const int m = lane & 15;
    const int g = lane >> 4;
    const int sw = (m & 7) << 4;

    f32x4 acc[8];
#pragma unroll
    for (int ct = 0; ct < 8; ++ct) acc[ct] = (f32x4){0.f, 0.f, 0.f, 0.f};

#pragma unroll
    for (int rel = 0; rel < 3; ++rel) {
        if (rel) __syncthreads();
        const unsigned short* Wg = Wt + (long)rel * 16384;
        for (int i = t; i < 2048; i += 256) {
            u32x4 v = *(const u32x4*)(Wg + i * 8);
            int byte = (i * 16) ^ (((i >> 4) & 7) << 4);
            *(u32x4*)((char*)Ws + byte) = v;
        }
        for (int i = t; i < 1024; i += 256) {
            int rr = i >> 4;
            int k8 = (i & 15) << 3;
            int row = row0 + rr;
            u32x4 v = (u32x4){0u, 0u, 0u, 0u};
            if (row < n) v = __builtin_nontemporal_load((const u32x4*)(A + (long)row * 384 + rel * HD + k8));
            int byte = (i * 16) ^ ((rr & 7) << 4);
            *(u32x4*)((char*)As + byte) = v;
        }
        __syncthreads();
#pragma unroll
        for (int ks = 0; ks < 4; ++ks) {
            const int kb = ks * 64 + g * 16;
            bf16x8 af = *(const bf16x8*)((const char*)As + ((((w * 16 + m) << 8) + kb) ^ sw));
#pragma unroll
            for (int ct = 0; ct < 8; ++ct) {
                bf16x8 bf = *(const bf16x8*)((const char*)Ws + ((((ct * 16 + m) << 8) + kb) ^ sw));
                acc[ct] = __builtin_amdgcn_mfma_f32_16x16x32_bf16(af, bf, acc[ct], 0, 0, 0);
            }
        }
    }

    if (MODE == 1) {
        unsigned short* C = (unsigned short*)Out;
#pragma unroll
        for (int ct = 0; ct < 8; ++ct) {
            float bv = bias[ct * 16 + m];
#pragma unroll
            for (int r = 0; r < 4; ++r) {
                int row = row0 + w * 16 + g * 4 + r;
                if (row < n)
                    C[(long)row * HD + ct * 16 + m] = f2bf(fmaxf(acc[ct][r] + bv, 0.f));
            }
        }
    } else {
        // ---- phase 2: h2 (LDS) @ kanW, then spline + fc ----
        __syncthreads();   // all phase-1 As reads done
#pragma unroll
        for (int ct = 0; ct < 8; ++ct) {
            float bv = bias[ct * 16 + m];
#pragma unroll
            for (int r = 0; r < 4; ++r) {
                int row = w * 16 + g * 4 + r;
                float hv = fmaxf(acc[ct][r] + bv, 0.f);
                int byte = ((row << 8) + ((ct * 16 + m) << 1)) ^ ((row & 7) << 4);
                *(unsigned short*)((char*)As + byte) = f2bf(hv);
            }
        }
        for (int i = t; i < 2048; i += 256) {
            u32x4 v = *(const u32x4*)(Wt2 + i * 8);
            int byte = (i * 16) ^ (((i >> 4) & 7) << 4);
            *(u32x4*)((char*)Ws + byte) = v;
        }
        __syncthreads();
#pragma unroll
        for (int ct = 0; ct < 8; ++ct) acc[ct] = (f32x4){0.f, 0.f, 0.f, 0.f};
#pragma unroll
        for (int ks = 0; ks < 4; ++ks) {
            const int kb = ks * 64 + g * 16;
            bf16x8 af = *(const bf16x8*)((const char*)As + ((((w * 16 + m) << 8) + kb) ^ sw));
#pragma unroll
            for (int ct = 0; ct < 8; ++ct) {
                bf16x8 bf = *(const bf16x8*)((const char*)Ws + ((((ct * 16 + m) << 8) + kb) ^ sw));
                acc[ct] = __builtin_amdgcn_mfma_f32_16x16x32_bf16(af, bf, acc[ct], 0, 0, 0);
            }
        }
        float kn[5];
#pragma unroll
        for (int i = 0; i < 5; ++i) kn[i] = knots[i];
        float part[4] = {0.f, 0.f, 0.f, 0.f};
#pragma unroll
        for (int ct = 0; ct < 8; ++ct) {
            int f = ct * 16 + m;
            float kb = bias2[f], al = alpha[f], be = beta[f], fw = fcw[f];
#pragma unroll
            for (int r = 0; r < 4; ++r) {
                float xv = al * (acc[ct][r] + kb) + be;
                int j = -1;
#pragma unroll
                for (int k = 0; k < 5; ++k) j += (xv >= kn[k]) ? 1 : 0;
                j = max(0, min(3, j));
                float t0 = kn[j], t1 = kn[j + 1];
                float hj = t1 - t0;
                float y0 = vals[f * 5 + j], y1 = vals[f * 5 + j + 1];
                float M0 = Msp[f * 5 + j], M1 = Msp[f * 5 + j + 1];
                float a = t1 - xv, b = xv - t0;
                float inv6h = 1.f / (6.f * hj);
                float s = M0 * a * a * a * inv6h + M1 * b * b * b * inv6h
                        + (y0 / hj - M0 * hj / 6.f) * a + (y1 / hj - M1 * hj / 6.f) * b;
                part[r] += s * fw;
            }
        }
#pragma unroll
        for (int o = 1; o < 16; o <<= 1) {
#pragma unroll
            for (int r = 0; r < 4; ++r) part[r] += __shfl_xor(part[r], o);
        }
        if (m == 0) {
#pragma unroll
            for (int r = 0; r < 4; ++r) {
                int row = row0 + w * 16 + g * 4 + r;
                if (row < n) ((float*)Out)[row] = part[r] + fcb[0];
            }
        }
    }
}

// ---------------- flat exclusive scan (phase A + C) ----------------------------
__global__ __launch_bounds__(256) void scanA(const int* __restrict__ cnt,
                                             int* __restrict__ S,
                                             int* __restrict__ bsum, int n) {
    __shared__ int ts[256];
    const int t = threadIdx.x;
    const int base = blockIdx.x * 2048 + t * 8;
    int v[8];
    int s = 0;
#pragma unroll
    for (int i = 0; i < 8; ++i) {
        int j = base + i;
        v[i] = (j < n) ? cnt[j] : 0;
        s += v[i];
    }
    ts[t] = s;
    __syncthreads();
    for (int off = 1; off < 256; off <<= 1) {
        int x = (t >= off) ? ts[t - off] : 0;
        __syncthreads();
        ts[t] += x;
        __syncthreads();
    }
    int excl = ts[t] - s;
#pragma unroll
    for (int i = 0; i < 8; ++i) {
        int j = base + i;
        if (j < n) S[j] = excl;
        excl += v[i];
    }
    if (t == 255) bsum[blockIdx.x] = ts[255];
}

__global__ __launch_bounds__(256) void scanC(int* __restrict__ S,
                                             const int* __restrict__ bsum,
                                             int n, int total) {
    __shared__ int red[256];
    const int t = threadIdx.x;
    int acc = 0;
    for (int b = t; b < blockIdx.x; b += 256) acc += bsum[b];
    red[t] = acc;
    __syncthreads();
    for (int o = 128; o; o >>= 1) {
        if (t < o) red[t] += red[t + o];
        __syncthreads();
    }
    const int off = red[0];
    const int base = blockIdx.x * 2048 + t * 8;
#pragma unroll
    for (int i = 0; i < 8; ++i) {
        int j = base + i;
        if (j < n) S[j] += off;
    }
    if (blockIdx.x == gridDim.x - 1 && t == 0) S[n] = total;
}

// ---------------- pass 2: write packed entries to block-private slots ----------
__global__ __launch_bounds__(256) void fill_pass(
    const int* __restrict__ e0, const int* __restrict__ e1,
    const int* __restrict__ e2, const int* __restrict__ O,
    unsigned int* __restrict__ P, int E, int NBLK, int NBUK) {
    __shared__ int cur[256];
    const int r = blockIdx.y, blk = blockIdx.x, t = threadIdx.x;
    const int* eb = (r == 0) ? e0 : ((r == 1) ? e1 : e2);
    if (t < NBUK) cur[t] = O[((long)r * NBUK + t) * NBLK + blk];
    __syncthreads();
    const int s0 = blk * EPB, s1 = min(s0 + EPB, E);
    for (int e = s0 + t; e < s1; e += 256) {
        int dst = eb[e], src = eb[E + e];
        int pos = atomicAdd(&cur[dst >> 8], 1);
        P[pos] = ((unsigned)(dst & 255) << 16) | (unsigned)src;
    }
}

// ---------------- pass 3: bucket -> dst-sorted srcs + per-dst rowptr S ---------
__global__ __launch_bounds__(256) void bucket_scatter2(
    const unsigned int* __restrict__ P, const int* __restrict__ O,
    unsigned short* __restrict__ srcs, int* __restrict__ S,
    int N, int NBUK, int NBLK, int E3) {
    __shared__ int cnt[256], pos[256], cur[256];
    const int b = blockIdx.x, r = blockIdx.y, t = threadIdx.x;
    const int d0 = b * BUK;
    const long oidx = (long)r * NBUK + b;
    const int pb = O[oidx * NBLK];
    const int pe = (oidx + 1 < (long)3 * NBUK) ? O[(oidx + 1) * NBLK] : E3;
    cnt[t] = 0;
    __syncthreads();
    for (int i = pb + t; i < pe; i += 256) atomicAdd(&cnt[P[i] >> 16], 1);
    __syncthreads();
    int v = cnt[t];
    pos[t] = v;
    __syncthreads();
    for (int off = 1; off < 256; off <<= 1) {
        int x = (t >= off) ? pos[t - off] : 0;
        __syncthreads();
        pos[t] += x;
        __syncthreads();
    }
    int start = pb + pos[t] - v;   // exclusive
    cur[t] = start;
    int d = d0 + t;
    if (d < N) S[(long)r * N + d] = start;
    __syncthreads();
    for (int i = pb + t; i < pe; i += 256) {
        unsigned pk = P[i];
        int p2 = atomicAdd(&cur[pk >> 16], 1);
        srcs[p2] = (unsigned short)(pk & 0xFFFFu);
    }
    if (b == NBUK - 1 && r == 2 && t == 0) S[(long)3 * N] = E3;
}

// ---------------- fused 3-relation gather agg: 16 lanes/dst, ushort8 loads -----
__global__ __launch_bounds__(256) void csr_agg3(const unsigned short* __restrict__ X,
                                                const int* __restrict__ S,
                                                const unsigned short* __restrict__ srcs,
                                                unsigned short* __restrict__ Ag, int N) {
    const int g = threadIdx.x >> 4;       // 16 groups per block
    const int lane = threadIdx.x & 15;    // 16 lanes x 8 feats = 128
    const int d = blockIdx.x * 16 + g;
    if (d >= N) return;
    const unsigned short* Xb = X + lane * 8;
#pragma unroll
    for (int r = 0; r < 3; ++r) {
        const int beg = S[(long)r * N + d];
        const int end = S[(long)r * N + d + 1];
        float ac[8] = {0.f, 0.f, 0.f, 0.f, 0.f, 0.f, 0.f, 0.f};
        int e = beg;
        for (; e + 7 < end; e += 8) {
            u32x4 v0 = *(const u32x4*)(Xb + (long)srcs[e    ] * HD);
            u32x4 v1 = *(const u32x4*)(Xb + (long)srcs[e + 1] * HD);
            u32x4 v2 = *(const u32x4*)(Xb + (long)srcs[e + 2] * HD);
            u32x4 v3 = *(const u32x4*)(Xb + (long)srcs[e + 3] * HD);
            u32x4 v4 = *(const u32x4*)(Xb + (long)srcs[e + 4] * HD);
            u32x4 v5 = *(const u32x4*)(Xb + (long)srcs[e + 5] * HD);
            u32x4 v6 = *(const u32x4*)(Xb + (long)srcs[e + 6] * HD);
            u32x4 v7 = *(const u32x4*)(Xb + (long)srcs[e + 7] * HD);
#pragma unroll
            for (int c = 0; c < 4; ++c) {
                ac[2*c]   += bf2f((unsigned short)(v0[c] & 0xffff)) + bf2f((unsigned short)(v1[c] & 0xffff))
                           + bf2f((unsigned short)(v2[c] & 0xffff)) + bf2f((unsigned short)(v3[c] & 0xffff))
                           + bf2f((unsigned short)(v4[c] & 0xffff)) + bf2f((unsigned short)(v5[c] & 0xffff))
                           + bf2f((unsigned short)(v6[c] & 0xffff)) + bf2f((unsigned short)(v7[c] & 0xffff));
                ac[2*c+1] += bf2f((unsigned short)(v0[c] >> 16)) + bf2f((unsigned short)(v1[c] >> 16))
                           + bf2f((unsigned short)(v2[c] >> 16)) + bf2f((unsigned short)(v3[c] >> 16))
                           + bf2f((unsigned short)(v4[c] >> 16)) + bf2f((unsigned short)(v5[c] >> 16))
                           + bf2f((unsigned short)(v6[c] >> 16)) + bf2f((unsigned short)(v7[c] >> 16));
            }
        }
        for (; e < end; ++e) {
            u32x4 v0 = *(const u32x4*)(Xb + (long)srcs[e] * HD);
#pragma unroll
            for (int c = 0; c < 4; ++c) {
                ac[2*c]   += bf2f((unsigned short)(v0[c] & 0xffff));
                ac[2*c+1] += bf2f((unsigned short)(v0[c] >> 16));
            }
        }
        u32x4 ov;
        ov[0] = (unsigned)f2bf(ac[0]) | ((unsigned)f2bf(ac[1]) << 16);
        ov[1] = (unsigned)f2bf(ac[2]) | ((unsigned)f2bf(ac[3]) << 16);
        ov[2] = (unsigned)f2bf(ac[4]) | ((unsigned)f2bf(ac[5]) << 16);
        ov[3] = (unsigned)f2bf(ac[6]) | ((unsigned)f2bf(ac[7]) << 16);
        __builtin_nontemporal_store(ov, (u32x4*)&Ag[(long)d * 384 + r * HD + lane * 8]);
    }
}

extern "C" void kernel_launch(void* const* d_in, const int* in_sizes, int n_in,
                              void* d_out, int out_size, void* d_ws, size_t ws_size,
                              hipStream_t stream) {
    const float* x       = (const float*)d_in[0];
    const int*   eA[3]   = {(const int*)d_in[1], (const int*)d_in[2], (const int*)d_in[3]};
    const float* W1      = (const float*)d_in[4];
    const float* lin1_w  = (const float*)d_in[5];
    const float* lin1_b  = (const float*)d_in[6];
    const float* W2      = (const float*)d_in[7];
    const float* lin2_w  = (const float*)d_in[8];
    const float* lin2_b  = (const float*)d_in[9];
    const float* kan_w   = (const float*)d_in[10];
    const float* kan_b   = (const float*)d_in[11];
    const float* alpha   = (const float*)d_in[12];
    const float* beta    = (const float*)d_in[13];
    const float* knots   = (const float*)d_in[14];
    const float* spline_vals = (const float*)d_in[15];
    const float* fc_w    = (const float*)d_in[16];
    const float* fc_b    = (const float*)d_in[17];

    const int N = in_sizes[0] / HD;
    const int E = in_sizes[1] / 2;
    const int NBUK = (N + BUK - 1) / BUK;
    const int NBLK = (E + EPB - 1) / EPB;
    const int nH   = 3 * NBUK * NBLK;      // histogram matrix size

    // ---- workspace carve (256B-aligned blocks) ----
    char* p = (char*)d_ws;
    auto carve = [&](size_t bytes) {
        char* q = p;
        p += (bytes + 255) & ~(size_t)255;
        return q;
    };
    float* M              = (float*)carve(4096);
    unsigned short* Wt    = (unsigned short*)carve((size_t)7 * 16384 * 2);
    int* Hmat             = (int*)carve((size_t)nH * 4);
    int* O                = (int*)carve((size_t)(nH + 1) * 4);
    int* bsum             = (int*)carve(4096);
    int* S                = (int*)carve((size_t)(3 * N + 1) * 4);
    unsigned int* P       = (unsigned int*)carve((size_t)3 * E * 4);
    unsigned short* srcs  = (unsigned short*)carve((size_t)3 * E * 2);
    unsigned short* xb    = (unsigned short*)carve((size_t)N * HD * 2);
    unsigned short* hb    = (unsigned short*)carve((size_t)N * HD * 2);
    unsigned short* Ag    = (unsigned short*)carve((size_t)N * 384 * 2);

    const long nxh = (long)N * HD;
    const int xcastB = (int)((nxh + 2047) / 2048);
    const int histBase = 1 + 896 + xcastB;
    const int prepGrid = histBase + 3 * NBLK;
    const int g64      = (N + 63) / 64;
    const int aggGrid  = (N + 15) / 16;
    const int scanGrid = (nH + 2047) / 2048;

    // fused small precomputes + edge histogram
    prep<<<prepGrid, 256, 0, stream>>>(knots, spline_vals, M, W1, W2, lin1_w, lin2_w,
                                       kan_w, Wt, x, xb, nxh,
                                       eA[0], eA[1], eA[2], Hmat, E, NBLK, NBUK, histBase);

    // ---- edge sort into dst-sorted srcs (block-private writes throughout) ----
    scanA<<<scanGrid, 256, 0, stream>>>(Hmat, O, bsum, nH);
    scanC<<<scanGrid, 256, 0, stream>>>(O, bsum, nH, 3 * E);
    fill_pass<<<dim3(NBLK, 3), 256, 0, stream>>>(eA[0], eA[1], eA[2], O, P, E, NBLK, NBUK);
    bucket_scatter2<<<dim3(NBUK, 3), 256, 0, stream>>>(P, O, srcs, S, N, NBUK, NBLK, 3 * E);

    // ---- layer 1: Ag = [A_r x]_cat ; h1 = relu(Ag @ [U1_r] + b1) ----
    csr_agg3<<<aggGrid, 256, 0, stream>>>(xb, S, srcs, Ag, N);
    mfma_gemm<1><<<g64, 256, 0, stream>>>(Ag, Wt, nullptr, hb, lin1_b, nullptr,
                                          nullptr, nullptr, nullptr, nullptr,
                                          nullptr, nullptr, nullptr, N);

    // ---- layer 2 + KAN + spline + fc (fused) ----
    csr_agg3<<<aggGrid, 256, 0, stream>>>(hb, S, srcs, Ag, N);
    mfma_gemm<3><<<g64, 256, 0, stream>>>(Ag, Wt + (size_t)3 * 16384,
                                          Wt + (size_t)6 * 16384, d_out, lin2_b, kan_b,
                                          alpha, beta, knots, spline_vals, M,
                                          fc_w, fc_b, N);
}

// Round 13
// 286.090 us; speedup vs baseline: 1.7824x; 1.0244x over previous
//
#include <hip/hip_runtime.h>

#define HD 128
#define EPB 4096   // edges per block in hist/fill passes
#define BUK 256    // dsts per bucket

typedef __attribute__((ext_vector_type(8))) short bf16x8;
typedef __attribute__((ext_vector_type(4))) float f32x4;
typedef __attribute__((ext_vector_type(4))) unsigned int u32x4;

static __device__ __forceinline__ float bf2f(unsigned short u) {
    union { unsigned int i; float f; } c; c.i = ((unsigned int)u) << 16; return c.f;
}
static __device__ __forceinline__ unsigned short f2bf(float f) {
    union { float f; unsigned int i; } c; c.f = f;
    unsigned int lsb = (c.i >> 16) & 1;
    c.i += 0x7fffu + lsb;
    return (unsigned short)(c.i >> 16);
}

// ------- fused prep: spline | U_r = W_r @ L^T | x->bf16 | edge histogram ------
__global__ __launch_bounds__(256) void prep(
    const float* __restrict__ knots, const float* __restrict__ vals,
    float* __restrict__ M,
    const float* __restrict__ W1, const float* __restrict__ W2,
    const float* __restrict__ l1, const float* __restrict__ l2,
    const float* __restrict__ kw, unsigned short* __restrict__ Wt,
    const float* __restrict__ x, unsigned short* __restrict__ xb, long nxh,
    const int* __restrict__ e0, const int* __restrict__ e1,
    const int* __restrict__ e2, int* __restrict__ Hmat,
    int E, int NBLK, int NBUK, int histBase) {
    const int bid = blockIdx.x;
    const int t = threadIdx.x;
    if (bid == 0) {
        if (t < 128) {
            int f = t;
            float kn[5], v[5];
#pragma unroll
            for (int i = 0; i < 5; ++i) { kn[i] = knots[i]; v[i] = vals[f * 5 + i]; }
            float h[4], sl[4];
#pragma unroll
            for (int i = 0; i < 4; ++i) { h[i] = kn[i+1] - kn[i]; sl[i] = (v[i+1] - v[i]) / h[i]; }
            float r0 = 6.f * (sl[1] - sl[0]);
            float r1 = 6.f * (sl[2] - sl[1]);
            float r2 = 6.f * (sl[3] - sl[2]);
            float d0 = 2.f * (h[0] + h[1]), d1 = 2.f * (h[1] + h[2]), d2 = 2.f * (h[2] + h[3]);
            float e0v = h[1], e1v = h[2];
            float w1 = e0v / d0;  float d1p = d1 - w1 * e0v;  float r1p = r1 - w1 * r0;
            float w2 = e1v / d1p; float d2p = d2 - w2 * e1v;  float r2p = r2 - w2 * r1p;
            float x2 = r2p / d2p;
            float x1 = (r1p - e1v * x2) / d1p;
            float x0 = (r0 - e0v * x1) / d0;
            M[f*5+0] = 0.f; M[f*5+1] = x0; M[f*5+2] = x1; M[f*5+3] = x2; M[f*5+4] = 0.f;
        }
        return;
    }
    if (bid < 897) {
        __shared__ float Lrow[HD];
        const int id = bid - 1;
        const int mat = id >> 7, c = id & 127;
        if (mat == 6) {
            if (t < 128) Wt[(long)6 * 16384 + c * HD + t] = f2bf(kw[c * HD + t]);
            return;
        }
        const float* Wr = (mat < 3) ? (W1 + (long)mat * 16384) : (W2 + (long)(mat - 3) * 16384);
        const float* L  = (mat < 3) ? l1 : l2;
        if (t < 128) Lrow[t] = L[c * HD + t];
        __syncthreads();
        if (t < 128) {
            float s = 0.f;
#pragma unroll 8
            for (int j = 0; j < HD; ++j) s += Wr[t * HD + j] * Lrow[j];
            Wt[(long)mat * 16384 + c * HD + t] = f2bf(s);
        }
        return;
    }
    if (bid < histBase) {
        long i = ((long)(bid - 897) * 256 + t) * 8;
        if (i < nxh) {
            float4 f0 = *(const float4*)(x + i);
            float4 f1 = *(const float4*)(x + i + 4);
            ushort4 o0, o1;
            o0.x = f2bf(f0.x); o0.y = f2bf(f0.y); o0.z = f2bf(f0.z); o0.w = f2bf(f0.w);
            o1.x = f2bf(f1.x); o1.y = f2bf(f1.y); o1.z = f2bf(f1.z); o1.w = f2bf(f1.w);
            *(ushort4*)(xb + i) = o0;
            *(ushort4*)(xb + i + 4) = o1;
        }
        return;
    }
    // histogram part
    __shared__ int hist[256];
    const int hid = bid - histBase;
    const int r = hid / NBLK, blk = hid - r * NBLK;
    const int* dst = (r == 0) ? e0 : ((r == 1) ? e1 : e2);
    if (t < NBUK) hist[t] = 0;
    __syncthreads();
    const int s0 = blk * EPB, s1 = min(s0 + EPB, E);
    for (int e = s0 + t; e < s1; e += 256) atomicAdd(&hist[dst[e] >> 8], 1);
    __syncthreads();
    if (t < NBUK) Hmat[((long)r * NBUK + t) * NBLK + blk] = hist[t];
}

// ---------------- MFMA GEMM -----------------------------------------------------
// MODE 1: hb(n x 128, bf16) = relu( Ag(n x 384, bf16) @ [U0;U1;U2] + bias )
// MODE 3: h2 = relu(Ag @ [U2] + bias) [LDS]; kanlin = h2 @ kanW + bias2;
//         affine -> spline -> dot fc_w -> out (n,)
template <int MODE>
__global__ __launch_bounds__(256) void mfma_gemm(
    const unsigned short* __restrict__ A, const unsigned short* __restrict__ Wt,
    const unsigned short* __restrict__ Wt2,
    void* __restrict__ Out, const float* __restrict__ bias,
    const float* __restrict__ bias2,
    const float* __restrict__ alpha, const float* __restrict__ beta,
    const float* __restrict__ knots, const float* __restrict__ vals,
    const float* __restrict__ Msp, const float* __restrict__ fcw,
    const float* __restrict__ fcb, int n) {
    __shared__ unsigned short As[64 * HD];   // 16 KB, XOR-swizzled
    __shared__ unsigned short Ws[HD * HD];   // 32 KB, XOR-swizzled
    const int t = threadIdx.x;
    const int row0 = blockIdx.x * 64;
    const int w = t >> 6;
    const int lane = t & 63;
    const int m = lane & 15;
    const int g = lane >> 4;
    const int sw = (m & 7) << 4;

    f32x4 acc[8];
#pragma unroll
    for (int ct = 0; ct < 8; ++ct) acc[ct] = (f32x4){0.f, 0.f, 0.f, 0.f};

#pragma unroll
    for (int rel = 0; rel < 3; ++rel) {
        if (rel) __syncthreads();
        const unsigned short* Wg = Wt + (long)rel * 16384;
        for (int i = t; i < 2048; i += 256) {
            u32x4 v = *(const u32x4*)(Wg + i * 8);
            int byte = (i * 16) ^ (((i >> 4) & 7) << 4);
            *(u32x4*)((char*)Ws + byte) = v;
        }
        for (int i = t; i < 1024; i += 256) {
            int rr = i >> 4;
            int k8 = (i & 15) << 3;
            int row = row0 + rr;
            u32x4 v = (u32x4){0u, 0u, 0u, 0u};
            if (row < n) v = __builtin_nontemporal_load((const u32x4*)(A + (long)row * 384 + rel * HD + k8));
            int byte = (i * 16) ^ ((rr & 7) << 4);
            *(u32x4*)((char*)As + byte) = v;
        }
        __syncthreads();
#pragma unroll
        for (int ks = 0; ks < 4; ++ks) {
            const int kb = ks * 64 + g * 16;
            bf16x8 af = *(const bf16x8*)((const char*)As + ((((w * 16 + m) << 8) + kb) ^ sw));
#pragma unroll
            for (int ct = 0; ct < 8; ++ct) {
                bf16x8 bf = *(const bf16x8*)((const char*)Ws + ((((ct * 16 + m) << 8) + kb) ^ sw));
                acc[ct] = __builtin_amdgcn_mfma_f32_16x16x32_bf16(af, bf, acc[ct], 0, 0, 0);
            }
        }
    }

    if (MODE == 1) {
        unsigned short* C = (unsigned short*)Out;
#pragma unroll
        for (int ct = 0; ct < 8; ++ct) {
            float bv = bias[ct * 16 + m];
#pragma unroll
            for (int r = 0; r < 4; ++r) {
                int row = row0 + w * 16 + g * 4 + r;
                if (row < n)
                    C[(long)row * HD + ct * 16 + m] = f2bf(fmaxf(acc[ct][r] + bv, 0.f));
            }
        }
    } else {
        // ---- phase 2: h2 (LDS) @ kanW, then spline + fc ----
        __syncthreads();   // all phase-1 As reads done
#pragma unroll
        for (int ct = 0; ct < 8; ++ct) {
            float bv = bias[ct * 16 + m];
#pragma unroll
            for (int r = 0; r < 4; ++r) {
                int row = w * 16 + g * 4 + r;
                float hv = fmaxf(acc[ct][r] + bv, 0.f);
                int byte = ((row << 8) + ((ct * 16 + m) << 1)) ^ ((row & 7) << 4);
                *(unsigned short*)((char*)As + byte) = f2bf(hv);
            }
        }
        for (int i = t; i < 2048; i += 256) {
            u32x4 v = *(const u32x4*)(Wt2 + i * 8);
            int byte = (i * 16) ^ (((i >> 4) & 7) << 4);
            *(u32x4*)((char*)Ws + byte) = v;
        }
        __syncthreads();
#pragma unroll
        for (int ct = 0; ct < 8; ++ct) acc[ct] = (f32x4){0.f, 0.f, 0.f, 0.f};
#pragma unroll
        for (int ks = 0; ks < 4; ++ks) {
            const int kb = ks * 64 + g * 16;
            bf16x8 af = *(const bf16x8*)((const char*)As + ((((w * 16 + m) << 8) + kb) ^ sw));
#pragma unroll
            for (int ct = 0; ct < 8; ++ct) {
                bf16x8 bf = *(const bf16x8*)((const char*)Ws + ((((ct * 16 + m) << 8) + kb) ^ sw));
                acc[ct] = __builtin_amdgcn_mfma_f32_16x16x32_bf16(af, bf, acc[ct], 0, 0, 0);
            }
        }
        float kn[5];
#pragma unroll
        for (int i = 0; i < 5; ++i) kn[i] = knots[i];
        float part[4] = {0.f, 0.f, 0.f, 0.f};
#pragma unroll
        for (int ct = 0; ct < 8; ++ct) {
            int f = ct * 16 + m;
            float kb = bias2[f], al = alpha[f], be = beta[f], fw = fcw[f];
#pragma unroll
            for (int r = 0; r < 4; ++r) {
                float xv = al * (acc[ct][r] + kb) + be;
                int j = -1;
#pragma unroll
                for (int k = 0; k < 5; ++k) j += (xv >= kn[k]) ? 1 : 0;
                j = max(0, min(3, j));
                float t0 = kn[j], t1 = kn[j + 1];
                float hj = t1 - t0;
                float y0 = vals[f * 5 + j], y1 = vals[f * 5 + j + 1];
                float M0 = Msp[f * 5 + j], M1 = Msp[f * 5 + j + 1];
                float a = t1 - xv, b = xv - t0;
                float inv6h = 1.f / (6.f * hj);
                float s = M0 * a * a * a * inv6h + M1 * b * b * b * inv6h
                        + (y0 / hj - M0 * hj / 6.f) * a + (y1 / hj - M1 * hj / 6.f) * b;
                part[r] += s * fw;
            }
        }
#pragma unroll
        for (int o = 1; o < 16; o <<= 1) {
#pragma unroll
            for (int r = 0; r < 4; ++r) part[r] += __shfl_xor(part[r], o);
        }
        if (m == 0) {
#pragma unroll
            for (int r = 0; r < 4; ++r) {
                int row = row0 + w * 16 + g * 4 + r;
                if (row < n) ((float*)Out)[row] = part[r] + fcb[0];
            }
        }
    }
}

// ---------------- flat exclusive scan (phase A + C) ----------------------------
__global__ __launch_bounds__(256) void scanA(const int* __restrict__ cnt,
                                             int* __restrict__ S,
                                             int* __restrict__ bsum, int n) {
    __shared__ int ts[256];
    const int t = threadIdx.x;
    const int base = blockIdx.x * 2048 + t * 8;
    int v[8];
    int s = 0;
#pragma unroll
    for (int i = 0; i < 8; ++i) {
        int j = base + i;
        v[i] = (j < n) ? cnt[j] : 0;
        s += v[i];
    }
    ts[t] = s;
    __syncthreads();
    for (int off = 1; off < 256; off <<= 1) {
        int x = (t >= off) ? ts[t - off] : 0;
        __syncthreads();
        ts[t] += x;
        __syncthreads();
    }
    int excl = ts[t] - s;
#pragma unroll
    for (int i = 0; i < 8; ++i) {
        int j = base + i;
        if (j < n) S[j] = excl;
        excl += v[i];
    }
    if (t == 255) bsum[blockIdx.x] = ts[255];
}

__global__ __launch_bounds__(256) void scanC(int* __restrict__ S,
                                             const int* __restrict__ bsum,
                                             int n, int total) {
    __shared__ int red[256];
    const int t = threadIdx.x;
    int acc = 0;
    for (int b = t; b < blockIdx.x; b += 256) acc += bsum[b];
    red[t] = acc;
    __syncthreads();
    for (int o = 128; o; o >>= 1) {
        if (t < o) red[t] += red[t + o];
        __syncthreads();
    }
    const int off = red[0];
    const int base = blockIdx.x * 2048 + t * 8;
#pragma unroll
    for (int i = 0; i < 8; ++i) {
        int j = base + i;
        if (j < n) S[j] += off;
    }
    if (blockIdx.x == gridDim.x - 1 && t == 0) S[n] = total;
}

// ---------------- pass 2: write packed entries to block-private slots ----------
__global__ __launch_bounds__(256) void fill_pass(
    const int* __restrict__ e0, const int* __restrict__ e1,
    const int* __restrict__ e2, const int* __restrict__ O,
    unsigned int* __restrict__ P, int E, int NBLK, int NBUK) {
    __shared__ int cur[256];
    const int r = blockIdx.y, blk = blockIdx.x, t = threadIdx.x;
    const int* eb = (r == 0) ? e0 : ((r == 1) ? e1 : e2);
    if (t < NBUK) cur[t] = O[((long)r * NBUK + t) * NBLK + blk];
    __syncthreads();
    const int s0 = blk * EPB, s1 = min(s0 + EPB, E);
    for (int e = s0 + t; e < s1; e += 256) {
        int dst = eb[e], src = eb[E + e];
        int pos = atomicAdd(&cur[dst >> 8], 1);
        P[pos] = ((unsigned)(dst & 255) << 16) | (unsigned)src;
    }
}

// ---------------- pass 3: bucket -> dst-sorted srcs + per-dst rowptr S ---------
__global__ __launch_bounds__(256) void bucket_scatter2(
    const unsigned int* __restrict__ P, const int* __restrict__ O,
    unsigned short* __restrict__ srcs, int* __restrict__ S,
    int N, int NBUK, int NBLK, int E3) {
    __shared__ int cnt[256], pos[256], cur[256];
    const int b = blockIdx.x, r = blockIdx.y, t = threadIdx.x;
    const int d0 = b * BUK;
    const long oidx = (long)r * NBUK + b;
    const int pb = O[oidx * NBLK];
    const int pe = (oidx + 1 < (long)3 * NBUK) ? O[(oidx + 1) * NBLK] : E3;
    cnt[t] = 0;
    __syncthreads();
    for (int i = pb + t; i < pe; i += 256) atomicAdd(&cnt[P[i] >> 16], 1);
    __syncthreads();
    int v = cnt[t];
    pos[t] = v;
    __syncthreads();
    for (int off = 1; off < 256; off <<= 1) {
        int x = (t >= off) ? pos[t - off] : 0;
        __syncthreads();
        pos[t] += x;
        __syncthreads();
    }
    int start = pb + pos[t] - v;   // exclusive
    cur[t] = start;
    int d = d0 + t;
    if (d < N) S[(long)r * N + d] = start;
    __syncthreads();
    for (int i = pb + t; i < pe; i += 256) {
        unsigned pk = P[i];
        int p2 = atomicAdd(&cur[pk >> 16], 1);
        srcs[p2] = (unsigned short)(pk & 0xFFFFu);
    }
    if (b == NBUK - 1 && r == 2 && t == 0) S[(long)3 * N] = E3;
}

// ---------------- fused 3-relation gather agg: 16 lanes/dst, ushort8 loads -----
__global__ __launch_bounds__(256) void csr_agg3(const unsigned short* __restrict__ X,
                                                const int* __restrict__ S,
                                                const unsigned short* __restrict__ srcs,
                                                unsigned short* __restrict__ Ag, int N) {
    const int g = threadIdx.x >> 4;       // 16 groups per block
    const int lane = threadIdx.x & 15;    // 16 lanes x 8 feats = 128
    const int d = blockIdx.x * 16 + g;
    if (d >= N) return;
    const unsigned short* Xb = X + lane * 8;
#pragma unroll
    for (int r = 0; r < 3; ++r) {
        const int beg = S[(long)r * N + d];
        const int end = S[(long)r * N + d + 1];
        float ac[8] = {0.f, 0.f, 0.f, 0.f, 0.f, 0.f, 0.f, 0.f};
        int e = beg;
        for (; e + 7 < end; e += 8) {
            u32x4 v0 = *(const u32x4*)(Xb + (long)srcs[e    ] * HD);
            u32x4 v1 = *(const u32x4*)(Xb + (long)srcs[e + 1] * HD);
            u32x4 v2 = *(const u32x4*)(Xb + (long)srcs[e + 2] * HD);
            u32x4 v3 = *(const u32x4*)(Xb + (long)srcs[e + 3] * HD);
            u32x4 v4 = *(const u32x4*)(Xb + (long)srcs[e + 4] * HD);
            u32x4 v5 = *(const u32x4*)(Xb + (long)srcs[e + 5] * HD);
            u32x4 v6 = *(const u32x4*)(Xb + (long)srcs[e + 6] * HD);
            u32x4 v7 = *(const u32x4*)(Xb + (long)srcs[e + 7] * HD);
#pragma unroll
            for (int c = 0; c < 4; ++c) {
                ac[2*c]   += bf2f((unsigned short)(v0[c] & 0xffff)) + bf2f((unsigned short)(v1[c] & 0xffff))
                           + bf2f((unsigned short)(v2[c] & 0xffff)) + bf2f((unsigned short)(v3[c] & 0xffff))
                           + bf2f((unsigned short)(v4[c] & 0xffff)) + bf2f((unsigned short)(v5[c] & 0xffff))
                           + bf2f((unsigned short)(v6[c] & 0xffff)) + bf2f((unsigned short)(v7[c] & 0xffff));
                ac[2*c+1] += bf2f((unsigned short)(v0[c] >> 16)) + bf2f((unsigned short)(v1[c] >> 16))
                           + bf2f((unsigned short)(v2[c] >> 16)) + bf2f((unsigned short)(v3[c] >> 16))
                           + bf2f((unsigned short)(v4[c] >> 16)) + bf2f((unsigned short)(v5[c] >> 16))
                           + bf2f((unsigned short)(v6[c] >> 16)) + bf2f((unsigned short)(v7[c] >> 16));
            }
        }
        for (; e < end; ++e) {
            u32x4 v0 = *(const u32x4*)(Xb + (long)srcs[e] * HD);
#pragma unroll
            for (int c = 0; c < 4; ++c) {
                ac[2*c]   += bf2f((unsigned short)(v0[c] & 0xffff));
                ac[2*c+1] += bf2f((unsigned short)(v0[c] >> 16));
            }
        }
        u32x4 ov;
        ov[0] = (unsigned)f2bf(ac[0]) | ((unsigned)f2bf(ac[1]) << 16);
        ov[1] = (unsigned)f2bf(ac[2]) | ((unsigned)f2bf(ac[3]) << 16);
        ov[2] = (unsigned)f2bf(ac[4]) | ((unsigned)f2bf(ac[5]) << 16);
        ov[3] = (unsigned)f2bf(ac[6]) | ((unsigned)f2bf(ac[7]) << 16);
        __builtin_nontemporal_store(ov, (u32x4*)&Ag[(long)d * 384 + r * HD + lane * 8]);
    }
}

extern "C" void kernel_launch(void* const* d_in, const int* in_sizes, int n_in,
                              void* d_out, int out_size, void* d_ws, size_t ws_size,
                              hipStream_t stream) {
    const float* x       = (const float*)d_in[0];
    const int*   eA[3]   = {(const int*)d_in[1], (const int*)d_in[2], (const int*)d_in[3]};
    const float* W1      = (const float*)d_in[4];
    const float* lin1_w  = (const float*)d_in[5];
    const float* lin1_b  = (const float*)d_in[6];
    const float* W2      = (const float*)d_in[7];
    const float* lin2_w  = (const float*)d_in[8];
    const float* lin2_b  = (const float*)d_in[9];
    const float* kan_w   = (const float*)d_in[10];
    const float* kan_b   = (const float*)d_in[11];
    const float* alpha   = (const float*)d_in[12];
    const float* beta    = (const float*)d_in[13];
    const float* knots   = (const float*)d_in[14];
    const float* spline_vals = (const float*)d_in[15];
    const float* fc_w    = (const float*)d_in[16];
    const float* fc_b    = (const float*)d_in[17];

    const int N = in_sizes[0] / HD;
    const int E = in_sizes[1] / 2;
    const int NBUK = (N + BUK - 1) / BUK;
    const int NBLK = (E + EPB - 1) / EPB;
    const int nH   = 3 * NBUK * NBLK;      // histogram matrix size

    // ---- workspace carve (256B-aligned blocks) ----
    char* p = (char*)d_ws;
    auto carve = [&](size_t bytes) {
        char* q = p;
        p += (bytes + 255) & ~(size_t)255;
        return q;
    };
    float* M              = (float*)carve(4096);
    unsigned short* Wt    = (unsigned short*)carve((size_t)7 * 16384 * 2);
    int* Hmat             = (int*)carve((size_t)nH * 4);
    int* O                = (int*)carve((size_t)(nH + 1) * 4);
    int* bsum             = (int*)carve(4096);
    int* S                = (int*)carve((size_t)(3 * N + 1) * 4);
    unsigned int* P       = (unsigned int*)carve((size_t)3 * E * 4);
    unsigned short* srcs  = (unsigned short*)carve((size_t)3 * E * 2);
    unsigned short* xb    = (unsigned short*)carve((size_t)N * HD * 2);
    unsigned short* hb    = (unsigned short*)carve((size_t)N * HD * 2);
    unsigned short* Ag    = (unsigned short*)carve((size_t)N * 384 * 2);

    const long nxh = (long)N * HD;
    const int xcastB = (int)((nxh + 2047) / 2048);
    const int histBase = 1 + 896 + xcastB;
    const int prepGrid = histBase + 3 * NBLK;
    const int g64      = (N + 63) / 64;
    const int aggGrid  = (N + 15) / 16;
    const int scanGrid = (nH + 2047) / 2048;

    // fused small precomputes + edge histogram
    prep<<<prepGrid, 256, 0, stream>>>(knots, spline_vals, M, W1, W2, lin1_w, lin2_w,
                                       kan_w, Wt, x, xb, nxh,
                                       eA[0], eA[1], eA[2], Hmat, E, NBLK, NBUK, histBase);

    // ---- edge sort into dst-sorted srcs (block-private writes throughout) ----
    scanA<<<scanGrid, 256, 0, stream>>>(Hmat, O, bsum, nH);
    scanC<<<scanGrid, 256, 0, stream>>>(O, bsum, nH, 3 * E);
    fill_pass<<<dim3(NBLK, 3), 256, 0, stream>>>(eA[0], eA[1], eA[2], O, P, E, NBLK, NBUK);
    bucket_scatter2<<<dim3(NBUK, 3), 256, 0, stream>>>(P, O, srcs, S, N, NBUK, NBLK, 3 * E);

    // ---- layer 1: Ag = [A_r x]_cat ; h1 = relu(Ag @ [U1_r] + b1) ----
    csr_agg3<<<aggGrid, 256, 0, stream>>>(xb, S, srcs, Ag, N);
    mfma_gemm<1><<<g64, 256, 0, stream>>>(Ag, Wt, nullptr, hb, lin1_b, nullptr,
                                          nullptr, nullptr, nullptr, nullptr,
                                          nullptr, nullptr, nullptr, N);

    // ---- layer 2 + KAN + spline + fc (fused) ----
    csr_agg3<<<aggGrid, 256, 0, stream>>>(hb, S, srcs, Ag, N);
    mfma_gemm<3><<<g64, 256, 0, stream>>>(Ag, Wt + (size_t)3 * 16384,
                                          Wt + (size_t)6 * 16384, d_out, lin2_b, kan_b,
                                          alpha, beta, knots, spline_vals, M,
                                          fc_w, fc_b, N);
}